// Round 1
// baseline (402.078 us; speedup 1.0000x reference)
//
#include <hip/hip_runtime.h>
#include <math.h>

#define Bn 4
#define Cn 64
#define Pn 4096   // 64*64
#define STR 68    // LDS row stride (floats): multiple of 4 -> float4 aligned; 68%32=4 -> breaks pow2 banks

// ---------------------------------------------------------------------------
// Kernel 1: per-pixel channel-vector L2 normalize.
// fg [B][C][P] -> Kn [B][P][C],  Kn[b,p,c] = fg[b,c,p] / (||fg[b,:,p]|| + 1e-8)
// ---------------------------------------------------------------------------
__global__ __launch_bounds__(256) void knorm_kernel(const float* __restrict__ fg,
                                                    float* __restrict__ Kn) {
    __shared__ float tile[64][65];
    __shared__ float rnorm[64];
    int b  = blockIdx.x >> 6;
    int p0 = (blockIdx.x & 63) << 6;
    int t  = threadIdx.x;
    const float* src = fg + (size_t)b * Cn * Pn + p0;
    int lp = t & 63, lg = t >> 6;
    #pragma unroll
    for (int i = 0; i < 16; ++i) {
        int c = i * 4 + lg;
        tile[c][lp] = src[(size_t)c * Pn + lp];   // coalesced over p
    }
    __syncthreads();
    if (t < 64) {
        float ss = 0.f;
        #pragma unroll
        for (int c = 0; c < 64; ++c) { float v = tile[c][t]; ss += v * v; }
        rnorm[t] = 1.0f / (sqrtf(ss) + 1e-8f);
    }
    __syncthreads();
    float* dst = Kn + (size_t)b * Pn * Cn + (size_t)p0 * Cn;
    int oc = t & 63, og = t >> 6;
    #pragma unroll
    for (int i = 0; i < 16; ++i) {
        int p = i * 4 + og;
        dst[(size_t)p * Cn + oc] = tile[oc][p] * rnorm[p];  // coalesced over c
    }
}

// ---------------------------------------------------------------------------
// Kernel 2: 3x3 zero-padded box sum per (b,c) plane.  fg [B][C][64][64] -> S same layout
// ---------------------------------------------------------------------------
__global__ __launch_bounds__(256) void boxsum_kernel(const float* __restrict__ fg,
                                                     float* __restrict__ S) {
    __shared__ float pl[64][64];
    int bc = blockIdx.x;                       // b*C + c
    const float* src = fg + (size_t)bc * Pn;
    float*       dst = S  + (size_t)bc * Pn;
    int t = threadIdx.x;
    #pragma unroll
    for (int i = 0; i < 16; ++i) {
        int idx = i * 256 + t;
        pl[idx >> 6][idx & 63] = src[idx];
    }
    __syncthreads();
    #pragma unroll
    for (int i = 0; i < 16; ++i) {
        int idx = i * 256 + t;
        int h = idx >> 6, w = idx & 63;
        float s = 0.f;
        #pragma unroll
        for (int dh = -1; dh <= 1; ++dh) {
            int hh = h + dh;
            if (hh < 0 || hh >= 64) continue;
            #pragma unroll
            for (int dw = -1; dw <= 1; ++dw) {
                int ww = w + dw;
                if (ww < 0 || ww >= 64) continue;
                s += pl[hh][ww];
            }
        }
        dst[idx] = s;
    }
}

// ---------------------------------------------------------------------------
// Kernel 3: flash-style  out[:,q] = Kn^T softmax_p(Kn · S[:,q])
// grid: B * 64 (q-tile = one image row, 64 columns); 256 threads.
// Streams p in blocks of 64 with online softmax.
// ---------------------------------------------------------------------------
__global__ __launch_bounds__(256) void flash_kernel(const float* __restrict__ Kn,
                                                    const float* __restrict__ S,
                                                    float* __restrict__ out) {
    __shared__ float Sl[64 * STR];     // Sl[c][q]
    __shared__ float Kl[64 * STR];     // Kl[p][c]
    __shared__ float El[64 * STR];     // El[p][q] scores -> exp
    __shared__ float marr[64], larr[64], alpha_s[64];
    __shared__ float red[4][64];

    int b  = blockIdx.x >> 6;
    int q0 = (blockIdx.x & 63) << 6;
    int t  = threadIdx.x;

    const float* Sg = S  + (size_t)b * Cn * Pn;   // [C][P]
    const float* Kg = Kn + (size_t)b * Pn * Cn;   // [P][C]

    // load S tile: Sl[c][qi] = Sg[c*P + q0+qi]
    {
        int lq = t & 63, lg = t >> 6;
        #pragma unroll
        for (int i = 0; i < 16; ++i) {
            int c = i * 4 + lg;
            Sl[c * STR + lq] = Sg[(size_t)c * Pn + q0 + lq];
        }
    }
    if (t < 64) { marr[t] = -INFINITY; larr[t] = 0.f; }

    // score phase mapping: 4x4 (p,q) per thread
    int qg = t & 15, pg = t >> 4;
    int q4 = qg * 4, p4 = pg * 4;
    // softmax phase mapping
    int sq = t & 63, srg = t >> 6;
    // accum phase mapping: 4x4 (c,q) per thread (same q4)
    int c4 = pg * 4;

    float acc[4][4];
    #pragma unroll
    for (int i = 0; i < 4; ++i)
        #pragma unroll
        for (int j = 0; j < 4; ++j) acc[i][j] = 0.f;

    __syncthreads();

    for (int pb = 0; pb < 64; ++pb) {
        // ---- load K tile [64p x 64c], contiguous 16 KB ----
        {
            const float4* src = (const float4*)(Kg + (size_t)(pb * 64) * Cn);
            #pragma unroll
            for (int i = 0; i < 4; ++i) {
                int idx = i * 256 + t;          // float4 index
                float4 v = src[idx];
                int p = idx >> 4;
                int c = (idx & 15) * 4;
                *(float4*)&Kl[p * STR + c] = v;
            }
        }
        __syncthreads();

        // ---- score phase: s[pi][qi] = sum_c Kl[p4+pi][c] * Sl[c][q4+qi] ----
        float s[4][4];
        #pragma unroll
        for (int i = 0; i < 4; ++i)
            #pragma unroll
            for (int j = 0; j < 4; ++j) s[i][j] = 0.f;
        #pragma unroll
        for (int c = 0; c < 64; c += 4) {
            float ka[4][4], sa[4][4];
            #pragma unroll
            for (int i = 0; i < 4; ++i) {
                float4 v = *(const float4*)&Kl[(p4 + i) * STR + c];
                ka[i][0] = v.x; ka[i][1] = v.y; ka[i][2] = v.z; ka[i][3] = v.w;
            }
            #pragma unroll
            for (int j = 0; j < 4; ++j) {
                float4 v = *(const float4*)&Sl[(c + j) * STR + q4];
                sa[j][0] = v.x; sa[j][1] = v.y; sa[j][2] = v.z; sa[j][3] = v.w;
            }
            #pragma unroll
            for (int i = 0; i < 4; ++i)
                #pragma unroll
                for (int j = 0; j < 4; ++j)
                    #pragma unroll
                    for (int cc = 0; cc < 4; ++cc)
                        s[i][j] += ka[i][cc] * sa[cc][j];
        }
        #pragma unroll
        for (int i = 0; i < 4; ++i)
            *(float4*)&El[(p4 + i) * STR + q4] = make_float4(s[i][0], s[i][1], s[i][2], s[i][3]);
        __syncthreads();

        // ---- online softmax: column (q) max over this p-block ----
        float lm = -INFINITY;
        #pragma unroll
        for (int r = 0; r < 16; ++r)
            lm = fmaxf(lm, El[(srg * 16 + r) * STR + sq]);
        red[srg][sq] = lm;
        __syncthreads();
        if (t < 64) {
            float cm   = fmaxf(fmaxf(red[0][t], red[1][t]), fmaxf(red[2][t], red[3][t]));
            float mOld = marr[t];
            float mNew = fmaxf(mOld, cm);
            marr[t]    = mNew;
            alpha_s[t] = __expf(mOld - mNew);   // exp(-inf)=0 on first block
        }
        __syncthreads();
        float mNew = marr[sq];
        float ls = 0.f;
        #pragma unroll
        for (int r = 0; r < 16; ++r) {
            int p = srg * 16 + r;
            float v = __expf(El[p * STR + sq] - mNew);
            El[p * STR + sq] = v;
            ls += v;
        }
        red[srg][sq] = ls;
        __syncthreads();
        if (t < 64)
            larr[t] = larr[t] * alpha_s[t] + (red[0][t] + red[1][t] + red[2][t] + red[3][t]);

        // ---- accumulate: acc[ci][qi] = alpha*acc + sum_p El[p][q4+qi]*Kl[p][c4+ci] ----
        {
            float4 al = *(const float4*)&alpha_s[q4];
            float av[4] = {al.x, al.y, al.z, al.w};
            #pragma unroll
            for (int i = 0; i < 4; ++i)
                #pragma unroll
                for (int j = 0; j < 4; ++j) acc[i][j] *= av[j];
            #pragma unroll 4
            for (int p = 0; p < 64; ++p) {
                float4 ev = *(const float4*)&El[p * STR + q4];
                float4 kv = *(const float4*)&Kl[p * STR + c4];
                float ea[4] = {ev.x, ev.y, ev.z, ev.w};
                float kb[4] = {kv.x, kv.y, kv.z, kv.w};
                #pragma unroll
                for (int i = 0; i < 4; ++i)
                    #pragma unroll
                    for (int j = 0; j < 4; ++j)
                        acc[i][j] += kb[i] * ea[j];
            }
        }
        __syncthreads();   // guards Kl/El overwrite next iter; makes larr visible after loop
    }

    // ---- epilogue: out[b][c][q] = acc / l[q] ----
    float4 lv = *(const float4*)&larr[q4];
    float li[4] = {lv.x, lv.y, lv.z, lv.w};
    float* og = out + (size_t)b * Cn * Pn;
    #pragma unroll
    for (int i = 0; i < 4; ++i) {
        float4 o;
        o.x = acc[i][0] / li[0];
        o.y = acc[i][1] / li[1];
        o.z = acc[i][2] / li[2];
        o.w = acc[i][3] / li[3];
        *(float4*)&og[(size_t)(c4 + i) * Pn + q0 + q4] = o;
    }
}

// ---------------------------------------------------------------------------
extern "C" void kernel_launch(void* const* d_in, const int* in_sizes, int n_in,
                              void* d_out, int out_size, void* d_ws, size_t ws_size,
                              hipStream_t stream) {
    const float* fg = (const float*)d_in[0];
    // d_in[1] (masks) is unused by the reference's first-call path.
    float* out = (float*)d_out;
    float* Kn  = (float*)d_ws;                      // 4 MB  [B][P][C]
    float* S   = Kn + (size_t)Bn * Pn * Cn;         // 4 MB  [B][C][P]

    knorm_kernel <<<Bn * 64, 256, 0, stream>>>(fg, Kn);
    boxsum_kernel<<<Bn * Cn, 256, 0, stream>>>(fg, S);
    flash_kernel <<<Bn * 64, 256, 0, stream>>>(Kn, S, out);
}

// Round 2
// 135.496 us; speedup vs baseline: 2.9674x; 2.9674x over previous
//
#include <hip/hip_runtime.h>
#include <math.h>

#define Bn 4
#define Cn 64
#define Pn 4096   // 64*64
#define QT 32     // q-tile per block
#define PBK 128   // p-block per flash iteration
#define SKpc 72   // LDS stride (bf16 elems) for Kl_pc rows of 64
#define SKcp 136  // LDS stride for Kl_cp rows of 128
#define SSl 72    // LDS stride for Sl rows of 64
#define SEl 136   // LDS stride for El rows of 128

typedef __attribute__((ext_vector_type(8))) short short8;   // 8 bf16 = 4 VGPRs (MFMA A/B frag)
typedef __attribute__((ext_vector_type(4))) float float4v;  // MFMA C/D frag
typedef unsigned short bfu;

__device__ __forceinline__ bfu f2bf(float x) {
    unsigned u = __float_as_uint(x);
    u = (u + 0x7fffu + ((u >> 16) & 1u)) >> 16;   // RNE; inputs are finite
    return (bfu)u;
}

// ---------------------------------------------------------------------------
// Kernel 1: L2-normalize per-pixel channel vectors; emit bf16 K in BOTH layouts:
//   Kpc [B][P][C]  (score-GEMM A operand), Kcp [B][C][P] (accum-GEMM A operand)
// ---------------------------------------------------------------------------
__global__ __launch_bounds__(256) void knorm_kernel(const float* __restrict__ fg,
                                                    bfu* __restrict__ Kpc,
                                                    bfu* __restrict__ Kcp) {
    __shared__ float tile[64][65];
    __shared__ float rnorm[64];
    int b  = blockIdx.x >> 6;
    int p0 = (blockIdx.x & 63) << 6;
    int t  = threadIdx.x;
    const float* src = fg + (size_t)b * Cn * Pn + p0;
    int lp = t & 63, lg = t >> 6;
    #pragma unroll
    for (int i = 0; i < 16; ++i) {
        int c = i * 4 + lg;
        tile[c][lp] = src[(size_t)c * Pn + lp];   // coalesced over p
    }
    __syncthreads();
    if (t < 64) {
        float ss = 0.f;
        #pragma unroll
        for (int c = 0; c < 64; ++c) { float v = tile[c][t]; ss += v * v; }
        rnorm[t] = 1.0f / (sqrtf(ss) + 1e-8f);
    }
    __syncthreads();
    bfu* dpc = Kpc + (size_t)b * Pn * Cn + (size_t)p0 * Cn;
    int oc = t & 63, og = t >> 6;
    #pragma unroll
    for (int i = 0; i < 16; ++i) {
        int p = i * 4 + og;
        dpc[(size_t)p * Cn + oc] = f2bf(tile[oc][p] * rnorm[p]);  // coalesced over c
    }
    bfu* dcp = Kcp + (size_t)b * Cn * Pn + p0;
    #pragma unroll
    for (int i = 0; i < 16; ++i) {
        int c = i * 4 + lg;
        dcp[(size_t)c * Pn + lp] = f2bf(tile[c][lp] * rnorm[lp]); // coalesced over p
    }
}

// ---------------------------------------------------------------------------
// Kernel 2: 3x3 zero-padded box sum per (b,c) plane (fp32 out, quantized later)
// ---------------------------------------------------------------------------
__global__ __launch_bounds__(256) void boxsum_kernel(const float* __restrict__ fg,
                                                     float* __restrict__ S) {
    __shared__ float pl[64][64];
    int bc = blockIdx.x;
    const float* src = fg + (size_t)bc * Pn;
    float*       dst = S  + (size_t)bc * Pn;
    int t = threadIdx.x;
    #pragma unroll
    for (int i = 0; i < 16; ++i) {
        int idx = i * 256 + t;
        pl[idx >> 6][idx & 63] = src[idx];
    }
    __syncthreads();
    #pragma unroll
    for (int i = 0; i < 16; ++i) {
        int idx = i * 256 + t;
        int h = idx >> 6, w = idx & 63;
        float s = 0.f;
        #pragma unroll
        for (int dh = -1; dh <= 1; ++dh) {
            int hh = h + dh;
            if (hh < 0 || hh >= 64) continue;
            #pragma unroll
            for (int dw = -1; dw <= 1; ++dw) {
                int ww = w + dw;
                if (ww < 0 || ww >= 64) continue;
                s += pl[hh][ww];
            }
        }
        dst[idx] = s;
    }
}

// ---------------------------------------------------------------------------
// Kernel 3: MFMA flash  out[:,q] = K^T softmax_p(K · S[:,q])
// grid = B * 128 (q-tile 32); 256 threads = 4 waves; p streamed in blocks of 128.
// Wave w: score rows p in [32w,32w+32); accum rows c in [16w,16w+16).
// ---------------------------------------------------------------------------
__global__ __launch_bounds__(256, 2) void flash_kernel(const bfu* __restrict__ Kpc,
                                                       const bfu* __restrict__ Kcp,
                                                       const float* __restrict__ S,
                                                       float* __restrict__ out) {
    __shared__ bfu Kl_pc[PBK * SKpc];   // [p][c]  score A
    __shared__ bfu Kl_cp[Cn * SKcp];    // [c][p]  accum A
    __shared__ bfu Sl[QT * SSl];        // [q][c]  score B
    __shared__ bfu El[QT * SEl];        // [q][p]  accum B (exp scores, bf16)
    __shared__ float wredm[4][QT];
    __shared__ float wredl[4][QT];
    __shared__ float marr[QT], larr[QT], alpha_s[QT];

    int b  = blockIdx.x >> 7;
    int q0 = (blockIdx.x & 127) * QT;
    int t  = threadIdx.x;
    int w = t >> 6, l = t & 63, lq = l & 15, quad = l >> 4;

    const float* Sg = S + (size_t)b * Cn * Pn;

    // prologue: Sl[q][c] = bf16(Sg[c][q0+q])   (once per block)
    {
        int c = t >> 2, qq = (t & 3) * 8;
        const float* sp = &Sg[(size_t)c * Pn + q0 + qq];
        float4 v0 = *(const float4*)sp;
        float4 v1 = *(const float4*)(sp + 4);
        float vv[8] = {v0.x, v0.y, v0.z, v0.w, v1.x, v1.y, v1.z, v1.w};
        #pragma unroll
        for (int i = 0; i < 8; ++i) Sl[(qq + i) * SSl + c] = f2bf(vv[i]);
    }
    if (t < QT) { marr[t] = -INFINITY; larr[t] = 0.f; }
    __syncthreads();

    // S B-frags are loop-invariant: hoist.  B[k=c][n=q]: n=lq, k=quad*8+j (+32ks)
    short8 bs[2][2];
    #pragma unroll
    for (int nt = 0; nt < 2; ++nt)
        #pragma unroll
        for (int ks = 0; ks < 2; ++ks)
            bs[nt][ks] = *(const short8*)&Sl[(nt * 16 + lq) * SSl + ks * 32 + quad * 8];

    float4v o[2];
    o[0] = (float4v){0.f, 0.f, 0.f, 0.f};
    o[1] = (float4v){0.f, 0.f, 0.f, 0.f};

    const bfu* gcp = Kcp + (size_t)b * Cn * Pn;

    for (int pb = 0; pb < Pn / PBK; ++pb) {
        // ---- stage K tiles (bf16, 16 KB each) ----
        {
            const float4* gsrc = (const float4*)(Kpc + ((size_t)b * Pn + (size_t)pb * PBK) * Cn);
            #pragma unroll
            for (int i = 0; i < 4; ++i) {
                int idx = i * 256 + t;            // 16B chunk
                float4 v = gsrc[idx];
                int p = idx >> 3, cc = (idx & 7) * 8;
                *(float4*)&Kl_pc[p * SKpc + cc] = v;
            }
            #pragma unroll
            for (int i = 0; i < 4; ++i) {
                int idx = i * 256 + t;
                int c = idx >> 4, pc = (idx & 15) * 8;
                float4 v = *(const float4*)&gcp[(size_t)c * Pn + pb * PBK + pc];
                *(float4*)&Kl_cp[c * SKcp + pc] = v;
            }
        }
        __syncthreads();

        // ---- score GEMM: sc[mt][nt] = K(p-rows) · S ----
        short8 af[2][2];
        #pragma unroll
        for (int mt = 0; mt < 2; ++mt)
            #pragma unroll
            for (int ks = 0; ks < 2; ++ks)
                af[mt][ks] = *(const short8*)&Kl_pc[(w * 32 + mt * 16 + lq) * SKpc + ks * 32 + quad * 8];
        float4v sc[2][2];
        #pragma unroll
        for (int mt = 0; mt < 2; ++mt)
            #pragma unroll
            for (int nt = 0; nt < 2; ++nt) {
                float4v acc = (float4v){0.f, 0.f, 0.f, 0.f};
                acc = __builtin_amdgcn_mfma_f32_16x16x32_bf16(af[mt][0], bs[nt][0], acc, 0, 0, 0);
                acc = __builtin_amdgcn_mfma_f32_16x16x32_bf16(af[mt][1], bs[nt][1], acc, 0, 0, 0);
                sc[mt][nt] = acc;
            }

        // ---- online softmax over p (rows) ----
        // lane holds q = nt*16+lq, p = 32w + 16mt + 4quad + r
        #pragma unroll
        for (int nt = 0; nt < 2; ++nt) {
            float mx = -INFINITY;
            #pragma unroll
            for (int mt = 0; mt < 2; ++mt)
                #pragma unroll
                for (int r = 0; r < 4; ++r) mx = fmaxf(mx, sc[mt][nt][r]);
            mx = fmaxf(mx, __shfl_xor(mx, 16));
            mx = fmaxf(mx, __shfl_xor(mx, 32));
            if (quad == 0) wredm[w][nt * 16 + lq] = mx;
        }
        __syncthreads();
        if (t < QT) {
            float mb = fmaxf(fmaxf(wredm[0][t], wredm[1][t]), fmaxf(wredm[2][t], wredm[3][t]));
            float mo = marr[t];
            float mn = fmaxf(mo, mb);
            marr[t] = mn;
            alpha_s[t] = __expf(mo - mn);   // exp(-inf)=0 on first block
        }
        __syncthreads();
        #pragma unroll
        for (int nt = 0; nt < 2; ++nt) {
            float mn = marr[nt * 16 + lq];
            float lsum = 0.f;
            #pragma unroll
            for (int mt = 0; mt < 2; ++mt) {
                float e0 = __expf(sc[mt][nt][0] - mn);
                float e1 = __expf(sc[mt][nt][1] - mn);
                float e2 = __expf(sc[mt][nt][2] - mn);
                float e3 = __expf(sc[mt][nt][3] - mn);
                lsum += (e0 + e1) + (e2 + e3);
                ushort4 pk;
                pk.x = f2bf(e0); pk.y = f2bf(e1); pk.z = f2bf(e2); pk.w = f2bf(e3);
                *(ushort4*)&El[(nt * 16 + lq) * SEl + w * 32 + mt * 16 + quad * 4] = pk;
            }
            lsum += __shfl_xor(lsum, 16);
            lsum += __shfl_xor(lsum, 32);
            if (quad == 0) wredl[w][nt * 16 + lq] = lsum;
        }
        __syncthreads();
        if (t < QT)
            larr[t] = larr[t] * alpha_s[t] + ((wredl[0][t] + wredl[1][t]) + (wredl[2][t] + wredl[3][t]));

        // ---- accum GEMM: o[c-rows][q] = alpha*o + K_cp · E ----
        #pragma unroll
        for (int nt = 0; nt < 2; ++nt) {
            float av = alpha_s[nt * 16 + lq];
            #pragma unroll
            for (int r = 0; r < 4; ++r) o[nt][r] *= av;
        }
        #pragma unroll
        for (int ks = 0; ks < 4; ++ks) {
            short8 ak = *(const short8*)&Kl_cp[(w * 16 + lq) * SKcp + ks * 32 + quad * 8];
            #pragma unroll
            for (int nt = 0; nt < 2; ++nt) {
                short8 bk = *(const short8*)&El[(nt * 16 + lq) * SEl + ks * 32 + quad * 8];
                o[nt] = __builtin_amdgcn_mfma_f32_16x16x32_bf16(ak, bk, o[nt], 0, 0, 0);
            }
        }
        __syncthreads();   // protect K/E tiles before next staging
    }

    // ---- epilogue: out[c][q0+q] = o / l[q] ----
    float* og = out + (size_t)b * Cn * Pn;
    #pragma unroll
    for (int nt = 0; nt < 2; ++nt) {
        int q = nt * 16 + lq;
        float linv = 1.0f / larr[q];
        #pragma unroll
        for (int r = 0; r < 4; ++r) {
            int c = w * 16 + quad * 4 + r;
            og[(size_t)c * Pn + q0 + q] = o[nt][r] * linv;
        }
    }
}

// ---------------------------------------------------------------------------
extern "C" void kernel_launch(void* const* d_in, const int* in_sizes, int n_in,
                              void* d_out, int out_size, void* d_ws, size_t ws_size,
                              hipStream_t stream) {
    const float* fg = (const float*)d_in[0];
    float* out = (float*)d_out;
    bfu*   Kpc = (bfu*)d_ws;                               // 2 MB  bf16 [B][P][C]
    bfu*   Kcp = Kpc + (size_t)Bn * Pn * Cn;               // 2 MB  bf16 [B][C][P]
    float* S   = (float*)(Kcp + (size_t)Bn * Pn * Cn);     // 4 MB  fp32 [B][C][P]

    knorm_kernel <<<Bn * 64, 256, 0, stream>>>(fg, Kpc, Kcp);
    boxsum_kernel<<<Bn * Cn, 256, 0, stream>>>(fg, S);
    flash_kernel <<<Bn * 128, 256, 0, stream>>>(Kpc, Kcp, S, out);
}